// Round 1
// baseline (1241.003 us; speedup 1.0000x reference)
//
#include <hip/hip_runtime.h>
#include <stdint.h>

// GCN: 2×(GCNConv + ReLU) + linear head.
// Strategy: build CSR (by dst) once, reuse for both layers.
// s_l[i][f] = (h_l[i] @ W)[f] * dinv[i];  agg[i] = dinv[i]*(sum_{src->i} s[src] + s[i]) + b
// Wave-per-node, lane-per-feature (F=64 == wavefront size).

static constexpr int FIN = 22;

__global__ void k_zero(int* cnt, int N) {
  int i = blockIdx.x * blockDim.x + threadIdx.x;
  int stride = gridDim.x * blockDim.x;
  for (; i < N; i += stride) cnt[i] = 0;
}

// Detect whether edge_index is int64 or int32 on device.
// Values are in [0, N) (< 2^31, non-negative). If int64 (little-endian),
// every odd 32-bit word is a zero high-half. If int32, odd words are random
// src indices (nonzero w.p. ~1-1e-5 each). Sample 64 odd words.
__global__ void k_detect(const unsigned int* w, int E, int* flag) {
  int t = threadIdx.x;  // 64 threads, 1 block
  size_t pos = 2ull * ((size_t)t * (size_t)(E / 64)) + 1ull;  // < 2*E words, safe in both layouts
  unsigned v = w[pos];
  unsigned long long b = __ballot(v != 0u);
  if (t == 0) *flag = (b == 0ull) ? 1 : 0;  // 1 = int64
}

__device__ __forceinline__ int load_idx(const void* ei, size_t i, int is64) {
  return is64 ? (int)((const long long*)ei)[i] : ((const int*)ei)[i];
}

__global__ void k_count(const void* ei, const int* __restrict__ flag, int* cnt, int E) {
  int is64 = *flag;
  int i = blockIdx.x * blockDim.x + threadIdx.x;
  int stride = gridDim.x * blockDim.x;
  for (; i < E; i += stride) {
    int d = load_idx(ei, (size_t)E + (size_t)i, is64);
    atomicAdd(&cnt[d], 1);
  }
}

// Single-block exclusive scan of cnt -> row_ptr; also init fill counters and dinv.
__global__ void k_scan(const int* __restrict__ cnt, int* row_ptr, int* fillc,
                       float* dinv, int N) {
  __shared__ int sh[1024];
  int t = threadIdx.x;
  int chunk = (N + 1023) >> 10;
  int s0 = t * chunk;
  int s1 = min(s0 + chunk, N);
  int local = 0;
  for (int i = s0; i < s1; ++i) local += cnt[i];
  sh[t] = local;
  __syncthreads();
  for (int off = 1; off < 1024; off <<= 1) {
    int v = (t >= off) ? sh[t - off] : 0;
    __syncthreads();
    sh[t] += v;
    __syncthreads();
  }
  int run = sh[t] - local;  // exclusive prefix for this chunk
  for (int i = s0; i < s1; ++i) {
    row_ptr[i] = run;
    fillc[i] = run;
    int c = cnt[i];
    dinv[i] = rsqrtf((float)(c + 1));  // +1 self-loop
    run += c;
  }
  if (t == 1023) row_ptr[N] = run;
}

__global__ void k_fill(const void* ei, const int* __restrict__ flag, int* fillc,
                       int* colv, int E) {
  int is64 = *flag;
  int i = blockIdx.x * blockDim.x + threadIdx.x;
  int stride = gridDim.x * blockDim.x;
  for (; i < E; i += stride) {
    int s = load_idx(ei, (size_t)i, is64);
    int d = load_idx(ei, (size_t)E + (size_t)i, is64);
    int p = atomicAdd(&fillc[d], 1);
    colv[p] = s;
  }
}

// s1[i][f] = (x[i] @ W1)[f] * dinv[i].  One wave per node, lane = feature.
__global__ void k_xform1(const float* __restrict__ x, const float* __restrict__ W1,
                         const float* __restrict__ dinv, float* __restrict__ s1, int N) {
  __shared__ float w[FIN * 64];
  int t = threadIdx.x;
  for (int i = t; i < FIN * 64; i += blockDim.x) w[i] = W1[i];
  __syncthreads();
  int gw = (int)((blockIdx.x * blockDim.x + t) >> 6);
  int lane = t & 63;
  if (gw >= N) return;
  const float* xi = x + (size_t)gw * FIN;
  float acc = 0.f;
#pragma unroll
  for (int k = 0; k < FIN; ++k) acc += xi[k] * w[k * 64 + lane];
  s1[(size_t)gw * 64 + lane] = acc * dinv[gw];
}

// agg over CSR + bias + ReLU, then fused h1@W2, scaled by dinv -> s2.
__global__ void k_agg1(const float* __restrict__ s1, const int* __restrict__ row_ptr,
                       const int* __restrict__ colv, const float* __restrict__ dinv,
                       const float* __restrict__ b1, const float* __restrict__ W2,
                       float* __restrict__ s2, int N) {
  __shared__ float w2[64 * 64];
  int t = threadIdx.x;
  for (int i = t; i < 64 * 64; i += blockDim.x) w2[i] = W2[i];
  __syncthreads();
  int wib = t >> 6, lane = t & 63;
  int node = blockIdx.x * 4 + wib;
  int nc = min(node, N - 1);  // clamp so all threads stay active (no sync hazards)
  int start = row_ptr[nc], end = row_ptr[nc + 1];
  float acc = 0.f;
  for (int base = start; base < end; base += 64) {
    int m = min(64, end - base);
    int idx = (lane < m) ? colv[base + lane] : 0;  // coalesced 64-wide index load
    for (int j = 0; j < m; ++j) {
      int s = __shfl(idx, j);
      acc += s1[(size_t)s * 64 + lane];  // coalesced 256B gather
    }
  }
  float di = dinv[nc];
  float h = fmaxf(di * (acc + s1[(size_t)nc * 64 + lane]) + b1[lane], 0.f);
  // s2[f] = dinv * sum_k h[k] * W2[k][f], share h across lanes via shuffle
  float o = 0.f;
#pragma unroll 8
  for (int k = 0; k < 64; ++k) o += __shfl(h, k) * w2[k * 64 + lane];
  if (node < N) s2[(size_t)node * 64 + lane] = o * di;
}

// agg2 + bias + ReLU + final head (h2 @ Wf + bf), wave-reduced.
__global__ void k_agg2(const float* __restrict__ s2, const int* __restrict__ row_ptr,
                       const int* __restrict__ colv, const float* __restrict__ dinv,
                       const float* __restrict__ b2, const float* __restrict__ Wf,
                       const float* __restrict__ bf, float* __restrict__ out, int N) {
  int t = threadIdx.x;
  int wib = t >> 6, lane = t & 63;
  int node = blockIdx.x * 4 + wib;
  if (node >= N) return;
  int start = row_ptr[node], end = row_ptr[node + 1];
  float acc = 0.f;
  for (int base = start; base < end; base += 64) {
    int m = min(64, end - base);
    int idx = (lane < m) ? colv[base + lane] : 0;
    for (int j = 0; j < m; ++j) {
      int s = __shfl(idx, j);
      acc += s2[(size_t)s * 64 + lane];
    }
  }
  float di = dinv[node];
  float h = fmaxf(di * (acc + s2[(size_t)node * 64 + lane]) + b2[lane], 0.f);
  float v = h * Wf[lane];
#pragma unroll
  for (int off = 32; off > 0; off >>= 1) v += __shfl_down(v, off);
  if (lane == 0) out[node] = v + bf[0];
}

extern "C" void kernel_launch(void* const* d_in, const int* in_sizes, int n_in,
                              void* d_out, int out_size, void* d_ws, size_t ws_size,
                              hipStream_t stream) {
  const float* x  = (const float*)d_in[0];
  const void*  ei = d_in[1];
  const float* W1 = (const float*)d_in[2];
  const float* b1 = (const float*)d_in[3];
  const float* W2 = (const float*)d_in[4];
  const float* b2 = (const float*)d_in[5];
  const float* Wf = (const float*)d_in[6];
  const float* bf = (const float*)d_in[7];
  int N = in_sizes[0] / FIN;
  int E = in_sizes[1] / 2;
  float* outp = (float*)d_out;

  // workspace layout (256B aligned)
  char* p = (char*)d_ws;
  auto alloc = [&](size_t bytes) {
    void* r = (void*)p;
    p += (bytes + 255) & ~(size_t)255;
    return r;
  };
  int*   cnt     = (int*)alloc((size_t)N * 4);
  int*   row_ptr = (int*)alloc(((size_t)N + 1) * 4);
  int*   fillc   = (int*)alloc((size_t)N * 4);
  float* dinv    = (float*)alloc((size_t)N * 4);
  int*   flag    = (int*)alloc(256);
  int*   colv    = (int*)alloc((size_t)E * 4);
  float* s1      = (float*)alloc((size_t)N * 64 * 4);
  float* s2      = (float*)alloc((size_t)N * 64 * 4);
  (void)ws_size; (void)n_in; (void)out_size;

  int egrid = min((E + 255) / 256, 8192);
  int ngrid = (N + 255) / 256;
  int wgrid = (N + 3) / 4;  // 4 waves (=4 nodes) per 256-thread block

  k_zero  <<<ngrid, 256, 0, stream>>>(cnt, N);
  k_detect<<<1, 64, 0, stream>>>((const unsigned int*)ei, E, flag);
  k_count <<<egrid, 256, 0, stream>>>(ei, flag, cnt, E);
  k_scan  <<<1, 1024, 0, stream>>>(cnt, row_ptr, fillc, dinv, N);
  k_fill  <<<egrid, 256, 0, stream>>>(ei, flag, fillc, colv, E);
  k_xform1<<<wgrid, 256, 0, stream>>>(x, W1, dinv, s1, N);
  k_agg1  <<<wgrid, 256, 0, stream>>>(s1, row_ptr, colv, dinv, b1, W2, s2, N);
  k_agg2  <<<wgrid, 256, 0, stream>>>(s2, row_ptr, colv, dinv, b2, Wf, bf, outp, N);
}

// Round 2
// 1207.260 us; speedup vs baseline: 1.0279x; 1.0279x over previous
//
#include <hip/hip_runtime.h>
#include <stdint.h>

// GCN: 2×(GCNConv + ReLU) + linear head.
// CSR (by dst) built once, used for both layers.
// Linearity trick: agg(x@W) == agg(x)@W, so layer 1 aggregates raw 22-dim x.
//   xs[i]  = x[i]*dinv[i]                       (22-dim)
//   t1[i]  = dinv[i]*(Σ_{src->i} xs[src] + xs[i])
//   h1[i]  = relu(t1 @ W1 + b1);  s2[i] = h1[i]*dinv[i]   (64-dim)
//   t2[i]  = dinv[i]*(Σ s2[src] + s2[i])
//   h2[i]  = relu(t2 @ W2 + b2);  out[i] = h2 @ Wf + bf

static constexpr int FIN = 22;

__global__ void k_zero(int* cnt, int N) {
  int i = blockIdx.x * blockDim.x + threadIdx.x;
  int stride = gridDim.x * blockDim.x;
  for (; i < N; i += stride) cnt[i] = 0;
}

// Detect int64 vs int32 edge_index: sample 64 odd 32-bit words; all-zero => int64.
__global__ void k_detect(const unsigned int* w, int E, int* flag) {
  int t = threadIdx.x;
  size_t pos = 2ull * ((size_t)t * (size_t)(E / 64)) + 1ull;
  unsigned v = w[pos];
  unsigned long long b = __ballot(v != 0u);
  if (t == 0) *flag = (b == 0ull) ? 1 : 0;
}

__device__ __forceinline__ int load_idx(const void* ei, size_t i, int is64) {
  return is64 ? (int)((const long long*)ei)[i] : ((const int*)ei)[i];
}

__global__ void k_count(const void* ei, const int* __restrict__ flag, int* cnt, int E) {
  int is64 = *flag;
  int i = blockIdx.x * blockDim.x + threadIdx.x;
  int stride = gridDim.x * blockDim.x;
  for (; i < E; i += stride) {
    int d = load_idx(ei, (size_t)E + (size_t)i, is64);
    atomicAdd(&cnt[d], 1);
  }
}

// Single-block scan cnt -> row_ptr; init fill counters and dinv.
__global__ void k_scan(const int* __restrict__ cnt, int* row_ptr, int* fillc,
                       float* dinv, int N) {
  __shared__ int sh[1024];
  int t = threadIdx.x;
  int chunk = (N + 1023) >> 10;
  int s0 = t * chunk;
  int s1 = min(s0 + chunk, N);
  if (s0 > N) s0 = N;
  int local = 0;
  for (int i = s0; i < s1; ++i) local += cnt[i];
  sh[t] = local;
  __syncthreads();
  for (int off = 1; off < 1024; off <<= 1) {
    int v = (t >= off) ? sh[t - off] : 0;
    __syncthreads();
    sh[t] += v;
    __syncthreads();
  }
  int run = sh[t] - local;
  for (int i = s0; i < s1; ++i) {
    row_ptr[i] = run;
    fillc[i] = run;
    int c = cnt[i];
    dinv[i] = rsqrtf((float)(c + 1));
    run += c;
  }
  if (t == 1023) row_ptr[N] = run;
}

__global__ void k_fill(const void* ei, const int* __restrict__ flag, int* fillc,
                       int* colv, int E) {
  int is64 = *flag;
  int i = blockIdx.x * blockDim.x + threadIdx.x;
  int stride = gridDim.x * blockDim.x;
  for (; i < E; i += stride) {
    int s = load_idx(ei, (size_t)i, is64);
    int d = load_idx(ei, (size_t)E + (size_t)i, is64);
    int p = atomicAdd(&fillc[d], 1);
    colv[p] = s;
  }
}

// xs[i][f] = x[i][f] * dinv[i], element-parallel.
__global__ void k_xs(const float* __restrict__ x, const float* __restrict__ dinv,
                     float* __restrict__ xs, int total) {
  int i = blockIdx.x * blockDim.x + threadIdx.x;
  int stride = gridDim.x * blockDim.x;
  for (; i < total; i += stride) {
    xs[i] = x[i] * dinv[i / FIN];
  }
}

// Layer 1: aggregate 22-dim xs over CSR, transform by W1, relu, scale -> s2 (64-dim).
// One wave per node; gather packs 2 edges per wave (lanes 0-31 / 32-63).
__global__ void k_agg1(const float* __restrict__ xs, const int* __restrict__ row_ptr,
                       const int* __restrict__ colv, const float* __restrict__ dinv,
                       const float* __restrict__ W1, const float* __restrict__ b1,
                       float* __restrict__ s2, int N) {
  __shared__ float w1[FIN * 64];
  int t = threadIdx.x;
  for (int i = t; i < FIN * 64; i += blockDim.x) w1[i] = W1[i];
  __syncthreads();
  int wib = t >> 6, lane = t & 63;
  int node = blockIdx.x * 4 + wib;
  if (node >= N) return;
  int f = lane & 31, half = lane >> 5;
  int start = row_ptr[node], end = row_ptr[node + 1];
  float acc = 0.f;
  int pos = start;
  for (; pos + 64 <= end; pos += 64) {           // full chunks: unrolled, no masks
    int idx = colv[pos + lane];
#pragma unroll
    for (int p = 0; p < 64; p += 2) {
      int s0 = __shfl(idx, p);
      int s1 = __shfl(idx, p + 1);
      int s = half ? s1 : s0;
      float v = (f < FIN) ? xs[(size_t)s * FIN + f] : 0.f;
      acc += v;
    }
  }
  if (pos < end) {                                // tail (common case, deg<64)
    int m = end - pos;
    int idx = (lane < m) ? colv[pos + lane] : 0;
    for (int p = 0; p < m; p += 2) {
      int s0 = __shfl(idx, p);
      int s1 = __shfl(idx, p + 1);
      int e = p + half;
      int s = half ? s1 : s0;
      float v = (e < m && f < FIN) ? xs[(size_t)s * FIN + f] : 0.f;
      acc += v;
    }
  }
  acc += __shfl_xor(acc, 32);                     // combine the two edge-halves
  float di = dinv[node];
  float selfv = (lane < FIN) ? xs[(size_t)node * FIN + lane] : 0.f;
  float tv = di * ((lane < FIN ? acc : 0.f) + selfv);   // t1, valid on lanes 0..21
  // h1[lane] = relu( sum_k t1[k]*W1[k][lane] + b1[lane] )
  float o = 0.f;
#pragma unroll
  for (int k = 0; k < FIN; ++k) o += __shfl(tv, k) * w1[k * 64 + lane];
  float h = fmaxf(o + b1[lane], 0.f);
  s2[(size_t)node * 64 + lane] = h * di;
}

// Layer 2 + head: aggregate 64-dim s2, transform by W2, relu, dot Wf, +bf.
__global__ void k_agg2(const float* __restrict__ s2, const int* __restrict__ row_ptr,
                       const int* __restrict__ colv, const float* __restrict__ dinv,
                       const float* __restrict__ W2, const float* __restrict__ b2,
                       const float* __restrict__ Wf, const float* __restrict__ bf,
                       float* __restrict__ out, int N) {
  __shared__ float w2[64 * 64];
  int t = threadIdx.x;
  for (int i = t; i < 64 * 64; i += blockDim.x) w2[i] = W2[i];
  __syncthreads();
  int wib = t >> 6, lane = t & 63;
  int node = blockIdx.x * 4 + wib;
  if (node >= N) return;
  int start = row_ptr[node], end = row_ptr[node + 1];
  float acc = 0.f;
  int pos = start;
  for (; pos + 64 <= end; pos += 64) {
    int idx = colv[pos + lane];
#pragma unroll
    for (int p = 0; p < 64; ++p) {
      int s = __shfl(idx, p);
      acc += s2[(size_t)s * 64 + lane];
    }
  }
  if (pos < end) {
    int m = end - pos;
    int idx = (lane < m) ? colv[pos + lane] : 0;
    int j = 0;
    for (; j + 4 <= m; j += 4) {                  // 4 independent loads in flight
      int a0 = __shfl(idx, j), a1 = __shfl(idx, j + 1);
      int a2 = __shfl(idx, j + 2), a3 = __shfl(idx, j + 3);
      float v0 = s2[(size_t)a0 * 64 + lane];
      float v1 = s2[(size_t)a1 * 64 + lane];
      float v2 = s2[(size_t)a2 * 64 + lane];
      float v3 = s2[(size_t)a3 * 64 + lane];
      acc += v0; acc += v1; acc += v2; acc += v3;
    }
    for (; j < m; ++j) {
      int s = __shfl(idx, j);
      acc += s2[(size_t)s * 64 + lane];
    }
  }
  float di = dinv[node];
  float u = di * (acc + s2[(size_t)node * 64 + lane]);   // t2[lane]
  float o = 0.f;
#pragma unroll
  for (int k = 0; k < 64; ++k) o += __shfl(u, k) * w2[k * 64 + lane];
  float h = fmaxf(o + b2[lane], 0.f);
  float v = h * Wf[lane];
#pragma unroll
  for (int off = 32; off > 0; off >>= 1) v += __shfl_down(v, off);
  if (lane == 0) out[node] = v + bf[0];
}

extern "C" void kernel_launch(void* const* d_in, const int* in_sizes, int n_in,
                              void* d_out, int out_size, void* d_ws, size_t ws_size,
                              hipStream_t stream) {
  const float* x  = (const float*)d_in[0];
  const void*  ei = d_in[1];
  const float* W1 = (const float*)d_in[2];
  const float* b1 = (const float*)d_in[3];
  const float* W2 = (const float*)d_in[4];
  const float* b2 = (const float*)d_in[5];
  const float* Wf = (const float*)d_in[6];
  const float* bf = (const float*)d_in[7];
  int N = in_sizes[0] / FIN;
  int E = in_sizes[1] / 2;
  float* outp = (float*)d_out;

  char* p = (char*)d_ws;
  auto alloc = [&](size_t bytes) {
    void* r = (void*)p;
    p += (bytes + 255) & ~(size_t)255;
    return r;
  };
  int*   cnt     = (int*)alloc((size_t)N * 4);
  int*   row_ptr = (int*)alloc(((size_t)N + 1) * 4);
  int*   fillc   = (int*)alloc((size_t)N * 4);
  float* dinv    = (float*)alloc((size_t)N * 4);
  int*   flag    = (int*)alloc(256);
  int*   colv    = (int*)alloc((size_t)E * 4);
  float* xs      = (float*)alloc((size_t)N * FIN * 4);
  float* s2      = (float*)alloc((size_t)N * 64 * 4);
  (void)ws_size; (void)n_in; (void)out_size;

  int egrid = min((E + 255) / 256, 12544);
  int ngrid = (N + 255) / 256;
  int xgrid = min((N * FIN + 255) / 256, 8704);
  int wgrid = (N + 3) / 4;

  k_zero  <<<ngrid, 256, 0, stream>>>(cnt, N);
  k_detect<<<1, 64, 0, stream>>>((const unsigned int*)ei, E, flag);
  k_count <<<egrid, 256, 0, stream>>>(ei, flag, cnt, E);
  k_scan  <<<1, 1024, 0, stream>>>(cnt, row_ptr, fillc, dinv, N);
  k_fill  <<<egrid, 256, 0, stream>>>(ei, flag, fillc, colv, E);
  k_xs    <<<xgrid, 256, 0, stream>>>(x, dinv, xs, N * FIN);
  k_agg1  <<<wgrid, 256, 0, stream>>>(xs, row_ptr, colv, dinv, W1, b1, s2, N);
  k_agg2  <<<wgrid, 256, 0, stream>>>(s2, row_ptr, colv, dinv, W2, b2, Wf, bf, outp, N);
}

// Round 3
// 790.928 us; speedup vs baseline: 1.5690x; 1.5264x over previous
//
#include <hip/hip_runtime.h>
#include <stdint.h>

// GCN: 2×(GCNConv + ReLU) + linear head.
// CSR (by dst) built once per launch, used for both layers.
// Linearity: agg(x@W) == agg(x)@W, so layer 1 aggregates raw 22-dim x.
//   xs[i]  = x[i]*dinv[i]                       (22-dim)
//   t1[i]  = dinv[i]*(Σ_{src->i} xs[src] + xs[i])
//   h1[i]  = relu(t1 @ W1 + b1);  s2[i] = h1[i]*dinv[i]   (64-dim)
//   t2[i]  = dinv[i]*(Σ s2[src] + s2[i])
//   h2[i]  = relu(t2 @ W2 + b2);  out[i] = h2 @ Wf + bf
// Round 3: XCD-windowed k_fill (kill 16x write amplification via L2-resident
// colv windows; blockIdx%8 ~ XCD heuristic), parallel 3-kernel scan.

static constexpr int FIN = 22;
static constexpr int NWIN = 8;  // = XCD count

__global__ void k_zero(int* cnt, int N) {
  int i = blockIdx.x * blockDim.x + threadIdx.x;
  int stride = gridDim.x * blockDim.x;
  for (; i < N; i += stride) cnt[i] = 0;
}

// Detect int64 vs int32 edge_index: sample 64 odd 32-bit words; all-zero => int64.
__global__ void k_detect(const unsigned int* w, int E, int* flag) {
  int t = threadIdx.x;
  size_t pos = 2ull * ((size_t)t * (size_t)(E / 64)) + 1ull;
  unsigned v = w[pos];
  unsigned long long b = __ballot(v != 0u);
  if (t == 0) *flag = (b == 0ull) ? 1 : 0;
}

__device__ __forceinline__ int load_idx(const void* ei, size_t i, int is64) {
  return is64 ? (int)((const long long*)ei)[i] : ((const int*)ei)[i];
}

__global__ void k_count(const void* ei, const int* __restrict__ flag, int* cnt, int E) {
  int is64 = *flag;
  int i = blockIdx.x * blockDim.x + threadIdx.x;
  int stride = gridDim.x * blockDim.x;
  for (; i < E; i += stride) {
    int d = load_idx(ei, (size_t)E + (size_t)i, is64);
    atomicAdd(&cnt[d], 1);
  }
}

// ---- parallel exclusive scan of cnt (3 kernels) ----
// scan1: per-block (1024 nodes) reduction -> partial[b]
__global__ void k_scan1(const int* __restrict__ cnt, int* partial, int N) {
  __shared__ int sh[256];
  int b = blockIdx.x, t = threadIdx.x;
  int i0 = b * 1024 + t * 4;
  int s = 0;
#pragma unroll
  for (int k = 0; k < 4; ++k) {
    int i = i0 + k;
    if (i < N) s += cnt[i];
  }
  sh[t] = s;
  __syncthreads();
  for (int off = 128; off > 0; off >>= 1) {
    if (t < off) sh[t] += sh[t + off];
    __syncthreads();
  }
  if (t == 0) partial[b] = sh[0];
}

// scan2: single-block exclusive scan of partials (nb <= 128)
__global__ void k_scan2(int* partial, int nb) {
  __shared__ int sh[128];
  int t = threadIdx.x;
  int v = (t < nb) ? partial[t] : 0;
  sh[t] = v;
  __syncthreads();
  for (int off = 1; off < 128; off <<= 1) {
    int u = (t >= off) ? sh[t - off] : 0;
    __syncthreads();
    sh[t] += u;
    __syncthreads();
  }
  if (t < nb) partial[t] = sh[t] - v;
}

// scan3: per-block local scan + base -> row_ptr, fillc, dinv
__global__ void k_scan3(const int* __restrict__ cnt, const int* __restrict__ base,
                        int* row_ptr, int* fillc, float* dinv, int N) {
  __shared__ int sh[256];
  int b = blockIdx.x, t = threadIdx.x;
  int i0 = b * 1024 + t * 4;
  int c[4];
  int s = 0;
#pragma unroll
  for (int k = 0; k < 4; ++k) {
    int i = i0 + k;
    c[k] = (i < N) ? cnt[i] : 0;
    s += c[k];
  }
  sh[t] = s;
  __syncthreads();
  int v = s;
  for (int off = 1; off < 256; off <<= 1) {
    int u = (t >= off) ? sh[t - off] : 0;
    __syncthreads();
    sh[t] += u;
    __syncthreads();
  }
  int excl = sh[t] - v + base[b];
#pragma unroll
  for (int k = 0; k < 4; ++k) {
    int i = i0 + k;
    if (i < N) {
      row_ptr[i] = excl;
      fillc[i] = excl;
      dinv[i] = rsqrtf((float)(c[k] + 1));
      excl += c[k];
    }
  }
  if (b == gridDim.x - 1 && t == 255) row_ptr[N] = excl;  // == E
}

// XCD-windowed fill: window w handled only by blocks with blockIdx%NWIN==w,
// so each window's colv segment (~1.6MB) stays resident in one XCD's L2 and
// the 16 scattered 4B stores per line coalesce before a single writeback.
__global__ void k_fill_win(const void* ei, const int* __restrict__ flag, int* fillc,
                           int* colv, int E, int winsize) {
  int is64 = *flag;
  int win = blockIdx.x % NWIN;
  int lo = win * winsize, hi = lo + winsize;
  int nb = gridDim.x / NWIN;
  int bw = blockIdx.x / NWIN;
  long long i = (long long)bw * blockDim.x + threadIdx.x;
  long long stride = (long long)nb * blockDim.x;
  for (; i < E; i += stride) {
    int d = load_idx(ei, (size_t)E + (size_t)i, is64);
    if (d >= lo && d < hi) {
      int s = load_idx(ei, (size_t)i, is64);
      int p = atomicAdd(&fillc[d], 1);
      colv[p] = s;
    }
  }
}

// xs[i][f] = x[i][f] * dinv[i], element-parallel.
__global__ void k_xs(const float* __restrict__ x, const float* __restrict__ dinv,
                     float* __restrict__ xs, int total) {
  int i = blockIdx.x * blockDim.x + threadIdx.x;
  int stride = gridDim.x * blockDim.x;
  for (; i < total; i += stride) {
    xs[i] = x[i] * dinv[i / FIN];
  }
}

// Layer 1: aggregate 22-dim xs over CSR, transform by W1, relu, scale -> s2 (64-dim).
// One wave per node; gather packs 2 edges per wave (lanes 0-31 / 32-63).
__global__ void k_agg1(const float* __restrict__ xs, const int* __restrict__ row_ptr,
                       const int* __restrict__ colv, const float* __restrict__ dinv,
                       const float* __restrict__ W1, const float* __restrict__ b1,
                       float* __restrict__ s2, int N) {
  __shared__ float w1[FIN * 64];
  int t = threadIdx.x;
  for (int i = t; i < FIN * 64; i += blockDim.x) w1[i] = W1[i];
  __syncthreads();
  int wib = t >> 6, lane = t & 63;
  int node = blockIdx.x * 4 + wib;
  if (node >= N) return;
  int f = lane & 31, half = lane >> 5;
  int start = row_ptr[node], end = row_ptr[node + 1];
  float acc = 0.f;
  int pos = start;
  for (; pos + 64 <= end; pos += 64) {
    int idx = colv[pos + lane];
#pragma unroll
    for (int p = 0; p < 64; p += 2) {
      int s0 = __shfl(idx, p);
      int s1 = __shfl(idx, p + 1);
      int s = half ? s1 : s0;
      float v = (f < FIN) ? xs[(size_t)s * FIN + f] : 0.f;
      acc += v;
    }
  }
  if (pos < end) {
    int m = end - pos;
    int idx = (lane < m) ? colv[pos + lane] : 0;
    for (int p = 0; p < m; p += 2) {
      int s0 = __shfl(idx, p);
      int s1 = __shfl(idx, p + 1);
      int e = p + half;
      int s = half ? s1 : s0;
      float v = (e < m && f < FIN) ? xs[(size_t)s * FIN + f] : 0.f;
      acc += v;
    }
  }
  acc += __shfl_xor(acc, 32);
  float di = dinv[node];
  float selfv = (lane < FIN) ? xs[(size_t)node * FIN + lane] : 0.f;
  float tv = di * ((lane < FIN ? acc : 0.f) + selfv);
  float o = 0.f;
#pragma unroll
  for (int k = 0; k < FIN; ++k) o += __shfl(tv, k) * w1[k * 64 + lane];
  float h = fmaxf(o + b1[lane], 0.f);
  s2[(size_t)node * 64 + lane] = h * di;
}

// Layer 2 + head: aggregate 64-dim s2, transform by W2, relu, dot Wf, +bf.
__global__ void k_agg2(const float* __restrict__ s2, const int* __restrict__ row_ptr,
                       const int* __restrict__ colv, const float* __restrict__ dinv,
                       const float* __restrict__ W2, const float* __restrict__ b2,
                       const float* __restrict__ Wf, const float* __restrict__ bf,
                       float* __restrict__ out, int N) {
  __shared__ float w2[64 * 64];
  int t = threadIdx.x;
  for (int i = t; i < 64 * 64; i += blockDim.x) w2[i] = W2[i];
  __syncthreads();
  int wib = t >> 6, lane = t & 63;
  int node = blockIdx.x * 4 + wib;
  if (node >= N) return;
  int start = row_ptr[node], end = row_ptr[node + 1];
  float acc = 0.f;
  int pos = start;
  for (; pos + 64 <= end; pos += 64) {
    int idx = colv[pos + lane];
#pragma unroll
    for (int p = 0; p < 64; ++p) {
      int s = __shfl(idx, p);
      acc += s2[(size_t)s * 64 + lane];
    }
  }
  if (pos < end) {
    int m = end - pos;
    int idx = (lane < m) ? colv[pos + lane] : 0;
    int j = 0;
    for (; j + 4 <= m; j += 4) {
      int a0 = __shfl(idx, j), a1 = __shfl(idx, j + 1);
      int a2 = __shfl(idx, j + 2), a3 = __shfl(idx, j + 3);
      float v0 = s2[(size_t)a0 * 64 + lane];
      float v1 = s2[(size_t)a1 * 64 + lane];
      float v2 = s2[(size_t)a2 * 64 + lane];
      float v3 = s2[(size_t)a3 * 64 + lane];
      acc += v0; acc += v1; acc += v2; acc += v3;
    }
    for (; j < m; ++j) {
      int s = __shfl(idx, j);
      acc += s2[(size_t)s * 64 + lane];
    }
  }
  float di = dinv[node];
  float u = di * (acc + s2[(size_t)node * 64 + lane]);
  float o = 0.f;
#pragma unroll
  for (int k = 0; k < 64; ++k) o += __shfl(u, k) * w2[k * 64 + lane];
  float h = fmaxf(o + b2[lane], 0.f);
  float v = h * Wf[lane];
#pragma unroll
  for (int off = 32; off > 0; off >>= 1) v += __shfl_down(v, off);
  if (lane == 0) out[node] = v + bf[0];
}

extern "C" void kernel_launch(void* const* d_in, const int* in_sizes, int n_in,
                              void* d_out, int out_size, void* d_ws, size_t ws_size,
                              hipStream_t stream) {
  const float* x  = (const float*)d_in[0];
  const void*  ei = d_in[1];
  const float* W1 = (const float*)d_in[2];
  const float* b1 = (const float*)d_in[3];
  const float* W2 = (const float*)d_in[4];
  const float* b2 = (const float*)d_in[5];
  const float* Wf = (const float*)d_in[6];
  const float* bf = (const float*)d_in[7];
  int N = in_sizes[0] / FIN;
  int E = in_sizes[1] / 2;
  float* outp = (float*)d_out;

  char* p = (char*)d_ws;
  auto alloc = [&](size_t bytes) {
    void* r = (void*)p;
    p += (bytes + 255) & ~(size_t)255;
    return r;
  };
  int*   cnt     = (int*)alloc((size_t)N * 4);
  int*   row_ptr = (int*)alloc(((size_t)N + 1) * 4);
  int*   fillc   = (int*)alloc((size_t)N * 4);
  float* dinv    = (float*)alloc((size_t)N * 4);
  int*   flag    = (int*)alloc(256);
  int*   partial = (int*)alloc(1024);
  int*   colv    = (int*)alloc((size_t)E * 4);
  float* xs      = (float*)alloc((size_t)N * FIN * 4);
  float* s2      = (float*)alloc((size_t)N * 64 * 4);
  (void)ws_size; (void)n_in; (void)out_size;

  int egrid = min((E + 255) / 256, 12544);
  int ngrid = (N + 255) / 256;
  int sgrid = (N + 1023) / 1024;            // scan blocks (<=128)
  int xgrid = min((N * FIN + 255) / 256, 8704);
  int wgrid = (N + 3) / 4;
  int winsize = (N + NWIN - 1) / NWIN;

  k_zero    <<<ngrid, 256, 0, stream>>>(cnt, N);
  k_detect  <<<1, 64, 0, stream>>>((const unsigned int*)ei, E, flag);
  k_count   <<<egrid, 256, 0, stream>>>(ei, flag, cnt, E);
  k_scan1   <<<sgrid, 256, 0, stream>>>(cnt, partial, N);
  k_scan2   <<<1, 128, 0, stream>>>(partial, sgrid);
  k_scan3   <<<sgrid, 256, 0, stream>>>(cnt, partial, row_ptr, fillc, dinv, N);
  k_fill_win<<<2048, 256, 0, stream>>>(ei, flag, fillc, colv, E, winsize);
  k_xs      <<<xgrid, 256, 0, stream>>>(x, dinv, xs, N * FIN);
  k_agg1    <<<wgrid, 256, 0, stream>>>(xs, row_ptr, colv, dinv, W1, b1, s2, N);
  k_agg2    <<<wgrid, 256, 0, stream>>>(s2, row_ptr, colv, dinv, W2, b2, Wf, bf, outp, N);
}

// Round 4
// 589.282 us; speedup vs baseline: 2.1060x; 1.3422x over previous
//
#include <hip/hip_runtime.h>
#include <hip/hip_fp16.h>
#include <stdint.h>

// GCN: 2×(GCNConv + ReLU) + linear head.  CSR (by dst) built once per launch.
// Linearity: agg(x@W) == agg(x)@W, so layer 1 aggregates raw 22-dim x.
// Round 4: fp16 gather payloads (xs padded to one 64B line/row; s2 = 128B row),
// 8-edge ILP in gather loops, int32 edge compaction for the windowed fill.

static constexpr int FIN = 22;
static constexpr int NWIN = 8;   // = XCD count
static constexpr int XW = 16;    // xs row stride in __half2 words (64 B)

__global__ void k_zero(int* cnt, int N) {
  int i = blockIdx.x * blockDim.x + threadIdx.x;
  int stride = gridDim.x * blockDim.x;
  for (; i < N; i += stride) cnt[i] = 0;
}

// Detect int64 vs int32 edge_index: sample 64 odd 32-bit words; all-zero => int64.
__global__ void k_detect(const unsigned int* w, int E, int* flag) {
  int t = threadIdx.x;
  size_t pos = 2ull * ((size_t)t * (size_t)(E / 64)) + 1ull;
  unsigned v = w[pos];
  unsigned long long b = __ballot(v != 0u);
  if (t == 0) *flag = (b == 0ull) ? 1 : 0;
}

__device__ __forceinline__ int load_idx(const void* ei, size_t i, int is64) {
  return is64 ? (int)((const long long*)ei)[i] : ((const int*)ei)[i];
}

// count in-degree + compact edge list to int32.
__global__ void k_count(const void* ei, const int* __restrict__ flag, int* cnt,
                        int* src32, int* dst32, int E) {
  int is64 = *flag;
  int i = blockIdx.x * blockDim.x + threadIdx.x;
  int stride = gridDim.x * blockDim.x;
  for (; i < E; i += stride) {
    int s = load_idx(ei, (size_t)i, is64);
    int d = load_idx(ei, (size_t)E + (size_t)i, is64);
    src32[i] = s;
    dst32[i] = d;
    atomicAdd(&cnt[d], 1);
  }
}

// ---- parallel exclusive scan of cnt (3 kernels) ----
__global__ void k_scan1(const int* __restrict__ cnt, int* partial, int N) {
  __shared__ int sh[256];
  int b = blockIdx.x, t = threadIdx.x;
  int i0 = b * 1024 + t * 4;
  int s = 0;
#pragma unroll
  for (int k = 0; k < 4; ++k) {
    int i = i0 + k;
    if (i < N) s += cnt[i];
  }
  sh[t] = s;
  __syncthreads();
  for (int off = 128; off > 0; off >>= 1) {
    if (t < off) sh[t] += sh[t + off];
    __syncthreads();
  }
  if (t == 0) partial[b] = sh[0];
}

__global__ void k_scan2(int* partial, int nb) {
  __shared__ int sh[128];
  int t = threadIdx.x;
  int v = (t < nb) ? partial[t] : 0;
  sh[t] = v;
  __syncthreads();
  for (int off = 1; off < 128; off <<= 1) {
    int u = (t >= off) ? sh[t - off] : 0;
    __syncthreads();
    sh[t] += u;
    __syncthreads();
  }
  if (t < nb) partial[t] = sh[t] - v;
}

__global__ void k_scan3(const int* __restrict__ cnt, const int* __restrict__ base,
                        int* row_ptr, int* fillc, float* dinv, int N) {
  __shared__ int sh[256];
  int b = blockIdx.x, t = threadIdx.x;
  int i0 = b * 1024 + t * 4;
  int c[4];
  int s = 0;
#pragma unroll
  for (int k = 0; k < 4; ++k) {
    int i = i0 + k;
    c[k] = (i < N) ? cnt[i] : 0;
    s += c[k];
  }
  sh[t] = s;
  __syncthreads();
  int v = s;
  for (int off = 1; off < 256; off <<= 1) {
    int u = (t >= off) ? sh[t - off] : 0;
    __syncthreads();
    sh[t] += u;
    __syncthreads();
  }
  int excl = sh[t] - v + base[b];
#pragma unroll
  for (int k = 0; k < 4; ++k) {
    int i = i0 + k;
    if (i < N) {
      row_ptr[i] = excl;
      fillc[i] = excl;
      dinv[i] = rsqrtf((float)(c[k] + 1));
      excl += c[k];
    }
  }
  if (b == gridDim.x - 1 && t == 255) row_ptr[N] = excl;
}

// XCD-windowed fill over compacted int32 edges.
__global__ void k_fill_win(const int* __restrict__ src32, const int* __restrict__ dst32,
                           int* fillc, int* colv, int E, int winsize) {
  int win = blockIdx.x % NWIN;
  int lo = win * winsize, hi = lo + winsize;
  int nb = gridDim.x / NWIN;
  int bw = blockIdx.x / NWIN;
  long long i = (long long)bw * blockDim.x + threadIdx.x;
  long long stride = (long long)nb * blockDim.x;
  for (; i < E; i += stride) {
    int d = dst32[i];
    if (d >= lo && d < hi) {
      int s = src32[i];
      int p = atomicAdd(&fillc[d], 1);
      colv[p] = s;
    }
  }
}

// xs2[i][w] = half2( x[i][2w]*dinv[i], x[i][2w+1]*dinv[i] ), padded to XW words.
__global__ void k_xs(const float* __restrict__ x, const float* __restrict__ dinv,
                     __half2* __restrict__ xs2, int N) {
  int i = blockIdx.x * blockDim.x + threadIdx.x;
  int stride = gridDim.x * blockDim.x;
  int total = N * XW;
  for (; i < total; i += stride) {
    int node = i >> 4, w = i & (XW - 1);
    float a = 0.f, b = 0.f;
    if (2 * w < FIN) {
      float di = dinv[node];
      a = x[(size_t)node * FIN + 2 * w] * di;
      b = x[(size_t)node * FIN + 2 * w + 1] * di;   // FIN even, both valid
    }
    xs2[i] = __floats2half2_rn(a, b);
  }
}

// Layer 1: aggregate 22-dim xs (one 64B line per edge), transform W1, relu -> s2 (fp16).
// 4 edges per wave (16 lanes x half2 each); 8 edges in flight.
__global__ void k_agg1(const __half2* __restrict__ xs2, const int* __restrict__ row_ptr,
                       const int* __restrict__ colv, const float* __restrict__ dinv,
                       const float* __restrict__ W1, const float* __restrict__ b1,
                       __half* __restrict__ s2h, int N) {
  __shared__ float w1[FIN * 64];
  int t = threadIdx.x;
  for (int i = t; i < FIN * 64; i += blockDim.x) w1[i] = W1[i];
  __syncthreads();
  int wib = t >> 6, lane = t & 63;
  int node = blockIdx.x * 4 + wib;
  if (node >= N) return;
  int q = lane >> 4, f = lane & 15;
  int start = row_ptr[node], end = row_ptr[node + 1];
  float ax = 0.f, ay = 0.f;
  for (int pos = start; pos < end; pos += 64) {
    int m = min(64, end - pos);
    int idx = (lane < m) ? colv[pos + lane] : 0;
    int j = 0;
    for (; j + 8 <= m; j += 8) {
      int a0 = __shfl(idx, j + q);
      int a1 = __shfl(idx, j + 4 + q);
      __half2 v0 = xs2[(size_t)a0 * XW + f];
      __half2 v1 = xs2[(size_t)a1 * XW + f];
      float2 f0 = __half22float2(v0);
      float2 f1 = __half22float2(v1);
      ax += f0.x + f1.x;
      ay += f0.y + f1.y;
    }
    for (; j < m; j += 4) {
      int e = j + q;
      int a0 = __shfl(idx, min(e, m - 1));
      if (e < m) {
        float2 f0 = __half22float2(xs2[(size_t)a0 * XW + f]);
        ax += f0.x;
        ay += f0.y;
      }
    }
  }
  // combine the 4 edge-quarters
  ax += __shfl_xor(ax, 16); ay += __shfl_xor(ay, 16);
  ax += __shfl_xor(ax, 32); ay += __shfl_xor(ay, 32);
  float di = dinv[node];
  float2 selfv = __half22float2(xs2[(size_t)node * XW + f]);
  float tx = di * (ax + selfv.x);          // t1[2f]
  float ty = di * (ay + selfv.y);          // t1[2f+1]
  float o = 0.f;
#pragma unroll
  for (int k = 0; k < FIN; ++k) {
    float tk = __shfl((k & 1) ? ty : tx, k >> 1);
    o += tk * w1[k * 64 + lane];
  }
  float h = fmaxf(o + b1[lane], 0.f);
  s2h[(size_t)node * 64 + lane] = __float2half(h * di);
}

// Layer 2 + head: aggregate 64-dim fp16 s2 (two lines per edge), transform W2,
// relu, dot Wf.  2 edges per wave (32 lanes x half2); 8 edges in flight.
__global__ void k_agg2(const __half2* __restrict__ s2v, const int* __restrict__ row_ptr,
                       const int* __restrict__ colv, const float* __restrict__ dinv,
                       const float* __restrict__ W2, const float* __restrict__ b2,
                       const float* __restrict__ Wf, const float* __restrict__ bf,
                       float* __restrict__ out, int N) {
  __shared__ float w2[64 * 64];
  int t = threadIdx.x;
  for (int i = t; i < 64 * 64; i += blockDim.x) w2[i] = W2[i];
  __syncthreads();
  int wib = t >> 6, lane = t & 63;
  int node = blockIdx.x * 4 + wib;
  if (node >= N) return;
  int half = lane >> 5, f = lane & 31;
  int start = row_ptr[node], end = row_ptr[node + 1];
  float ax = 0.f, ay = 0.f;
  for (int pos = start; pos < end; pos += 64) {
    int m = min(64, end - pos);
    int idx = (lane < m) ? colv[pos + lane] : 0;
    int j = 0;
    for (; j + 8 <= m; j += 8) {
      int a0 = __shfl(idx, j + half);
      int a1 = __shfl(idx, j + 2 + half);
      int a2 = __shfl(idx, j + 4 + half);
      int a3 = __shfl(idx, j + 6 + half);
      __half2 v0 = s2v[(size_t)a0 * 32 + f];
      __half2 v1 = s2v[(size_t)a1 * 32 + f];
      __half2 v2 = s2v[(size_t)a2 * 32 + f];
      __half2 v3 = s2v[(size_t)a3 * 32 + f];
      float2 f0 = __half22float2(v0), f1 = __half22float2(v1);
      float2 f2 = __half22float2(v2), f3 = __half22float2(v3);
      ax += (f0.x + f1.x) + (f2.x + f3.x);
      ay += (f0.y + f1.y) + (f2.y + f3.y);
    }
    for (; j < m; j += 2) {
      int e = j + half;
      int a0 = __shfl(idx, min(e, m - 1));
      if (e < m) {
        float2 f0 = __half22float2(s2v[(size_t)a0 * 32 + f]);
        ax += f0.x;
        ay += f0.y;
      }
    }
  }
  ax += __shfl_xor(ax, 32);
  ay += __shfl_xor(ay, 32);
  float di = dinv[node];
  float2 selfv = __half22float2(s2v[(size_t)node * 32 + f]);
  float tx = di * (ax + selfv.x);          // t2[2f]
  float ty = di * (ay + selfv.y);          // t2[2f+1]
  float o = 0.f;
#pragma unroll
  for (int k = 0; k < 64; ++k) {
    float tk = __shfl((k & 1) ? ty : tx, k >> 1);
    o += tk * w2[k * 64 + lane];
  }
  float h = fmaxf(o + b2[lane], 0.f);
  float v = h * Wf[lane];
#pragma unroll
  for (int off = 32; off > 0; off >>= 1) v += __shfl_down(v, off);
  if (lane == 0) out[node] = v + bf[0];
}

extern "C" void kernel_launch(void* const* d_in, const int* in_sizes, int n_in,
                              void* d_out, int out_size, void* d_ws, size_t ws_size,
                              hipStream_t stream) {
  const float* x  = (const float*)d_in[0];
  const void*  ei = d_in[1];
  const float* W1 = (const float*)d_in[2];
  const float* b1 = (const float*)d_in[3];
  const float* W2 = (const float*)d_in[4];
  const float* b2 = (const float*)d_in[5];
  const float* Wf = (const float*)d_in[6];
  const float* bf = (const float*)d_in[7];
  int N = in_sizes[0] / FIN;
  int E = in_sizes[1] / 2;
  float* outp = (float*)d_out;

  char* p = (char*)d_ws;
  auto alloc = [&](size_t bytes) {
    void* r = (void*)p;
    p += (bytes + 255) & ~(size_t)255;
    return r;
  };
  int*     cnt     = (int*)alloc((size_t)N * 4);
  int*     row_ptr = (int*)alloc(((size_t)N + 1) * 4);
  int*     fillc   = (int*)alloc((size_t)N * 4);
  float*   dinv    = (float*)alloc((size_t)N * 4);
  int*     flag    = (int*)alloc(256);
  int*     partial = (int*)alloc(1024);
  int*     colv    = (int*)alloc((size_t)E * 4);
  int*     src32   = (int*)alloc((size_t)E * 4);
  int*     dst32   = (int*)alloc((size_t)E * 4);
  __half2* xs2     = (__half2*)alloc((size_t)N * XW * 4);
  __half*  s2h     = (__half*)alloc((size_t)N * 64 * 2);
  (void)ws_size; (void)n_in; (void)out_size;

  int egrid = min((E + 255) / 256, 12544);
  int ngrid = (N + 255) / 256;
  int sgrid = (N + 1023) / 1024;
  int xgrid = min((N * XW + 255) / 256, 8704);
  int wgrid = (N + 3) / 4;
  int winsize = (N + NWIN - 1) / NWIN;

  k_zero    <<<ngrid, 256, 0, stream>>>(cnt, N);
  k_detect  <<<1, 64, 0, stream>>>((const unsigned int*)ei, E, flag);
  k_count   <<<egrid, 256, 0, stream>>>(ei, flag, cnt, src32, dst32, E);
  k_scan1   <<<sgrid, 256, 0, stream>>>(cnt, partial, N);
  k_scan2   <<<1, 128, 0, stream>>>(partial, sgrid);
  k_scan3   <<<sgrid, 256, 0, stream>>>(cnt, partial, row_ptr, fillc, dinv, N);
  k_fill_win<<<2048, 256, 0, stream>>>(src32, dst32, fillc, colv, E, winsize);
  k_xs      <<<xgrid, 256, 0, stream>>>(x, dinv, xs2, N);
  k_agg1    <<<wgrid, 256, 0, stream>>>(xs2, row_ptr, colv, dinv, W1, b1, s2h, N);
  k_agg2    <<<wgrid, 256, 0, stream>>>((const __half2*)s2h, row_ptr, colv, dinv,
                                        W2, b2, Wf, bf, outp, N);
}